// Round 1
// baseline (19283.871 us; speedup 1.0000x reference)
//
#include <hip/hip_runtime.h>
#include <hip/hip_bf16.h>
#include <math.h>

// Problem constants
// B=8, T=32, P=32, N=16, D=128, H=4, C=16, HD=32, FFN_PCI=1024, MLP_H=512
// tokens = B*T*P*N = 131072, layout [B,T,P,N,D] flat; token = bt*512 + p*16 + n

static __device__ __forceinline__ float gelu_f(float v) {
    return 0.5f * v * (1.0f + erff(v * 0.70710678118654752f));
}

// ---------------------------------------------------------------------------
// Kernel 1: inter-patch PCI.  grid = B*T*N = 4096 blocks, 256 threads.
// Each block handles one (bt, n) group of P=32 rows x D=128.
// LDS (48KB): xi[32][128] | A (16KB multi-use) | Bx (16KB multi-use)
//   A : q[32][128] -> { ap2c[0:2048], vcore[2048:4096] } -> hidden[32][128]
//   Bx: { aff[0:2048], ac2p[2048:4096] } -> vout[32][128]
// ---------------------------------------------------------------------------
__global__ __launch_bounds__(256)
void pci_inter_kernel(const float* __restrict__ x,
                      const float* __restrict__ cores,   // [4][16][32]
                      const float* __restrict__ vw,      // [128][128]
                      const float* __restrict__ vb,      // [128]
                      const float* __restrict__ f1w,     // [256][1024]
                      const float* __restrict__ f1b,     // [1024]
                      const float* __restrict__ f2w,     // [1024][128]
                      const float* __restrict__ f2b,     // [128]
                      const float* __restrict__ ng,      // [128]
                      const float* __restrict__ nb,      // [128]
                      float* __restrict__ out)
{
    __shared__ float smem[12288];
    float* xi = smem;            // [32][128] LN'd input (persists)
    float* A  = smem + 4096;
    float* Bx = smem + 8192;

    const int t   = threadIdx.x;
    const int r   = t >> 3;      // row 0..31 (patch p)
    const int sub = t & 7;
    const int c0  = sub * 16;

    const int m  = blockIdx.x;
    const int n  = m & 15;
    const int bt = m >> 4;
    const long baseTok = (long)bt * 512 + n;   // token of row p is baseTok + p*16
    const float* xrow = x + (baseTok + (long)r * 16) * 128 + c0;

    // --- LN(eps=1e-6, non-affine) -> xi ---
    float v0[16];
    float s = 0.f, ss = 0.f;
    #pragma unroll
    for (int i = 0; i < 16; ++i) {
        v0[i] = xrow[i];
        s += v0[i]; ss += v0[i] * v0[i];
    }
    #pragma unroll
    for (int msk = 1; msk < 8; msk <<= 1) {
        s  += __shfl_xor(s,  msk);
        ss += __shfl_xor(ss, msk);
    }
    {
        float mean = s * (1.f / 128.f);
        float var  = ss * (1.f / 128.f) - mean * mean;
        float inv  = rsqrtf(var + 1e-6f);
        #pragma unroll
        for (int i = 0; i < 16; ++i) xi[r * 128 + c0 + i] = (v0[i] - mean) * inv;
    }
    __syncthreads();

    // --- q = xi @ vw + vb  -> A[0:4096] as q[32][128] ---
    {
        float a[16];
        #pragma unroll
        for (int i = 0; i < 16; ++i) a[i] = vb[c0 + i];
        for (int d = 0; d < 128; ++d) {
            float xv = xi[r * 128 + d];
            const float* wrow = vw + d * 128 + c0;
            #pragma unroll
            for (int i = 0; i < 16; ++i) a[i] = fmaf(xv, wrow[i], a[i]);
        }
        #pragma unroll
        for (int i = 0; i < 16; ++i) A[r * 128 + c0 + i] = a[i];
    }
    __syncthreads();

    // --- aff[h][c][p] = cores . q / sqrt(32) -> Bx[0:2048] ---
    for (int e = t; e < 2048; e += 256) {
        int p = e & 31, c = (e >> 5) & 15, h = e >> 9;
        const float* cr = cores + (h * 16 + c) * 32;
        const float* qr = A + p * 128 + h * 32;
        float a = 0.f;
        #pragma unroll
        for (int d = 0; d < 32; ++d) a = fmaf(cr[d], qr[d], a);
        Bx[e] = a * 0.17677669529663687f;   // 1/sqrt(32)
    }
    __syncthreads();

    // --- softmaxes: ac2p (over p) -> Bx[2048:4096];  ap2c (over c) -> A[0:2048]
    if (t < 64) {
        const float* arow = Bx + t * 32;             // (h,c) row
        float mx = -1e30f;
        #pragma unroll
        for (int p = 0; p < 32; ++p) mx = fmaxf(mx, arow[p]);
        float ex[32]; float sm = 0.f;
        #pragma unroll
        for (int p = 0; p < 32; ++p) { ex[p] = expf(arow[p] - mx); sm += ex[p]; }
        float is = 1.f / sm;
        #pragma unroll
        for (int p = 0; p < 32; ++p) Bx[2048 + t * 32 + p] = ex[p] * is;
    } else if (t < 192) {
        int u = t - 64;
        int h = u >> 5, p = u & 31;
        const float* ab = Bx + h * 512 + p;          // aff[h][c][p], stride 32 over c
        float mx = -1e30f;
        #pragma unroll
        for (int c = 0; c < 16; ++c) mx = fmaxf(mx, ab[c * 32]);
        float ex[16]; float sm = 0.f;
        #pragma unroll
        for (int c = 0; c < 16; ++c) { ex[c] = expf(ab[c * 32] - mx); sm += ex[c]; }
        float is = 1.f / sm;
        #pragma unroll
        for (int c = 0; c < 16; ++c) A[h * 512 + c * 32 + p] = ex[c] * is;
    }
    __syncthreads();

    // --- vcore[h][c][d] = sum_p xi[p][h*32+d] * ac2p[h][c][p] -> A[2048:4096]
    for (int e = t; e < 2048; e += 256) {
        int d = e & 31, c = (e >> 5) & 15, h = e >> 9;
        const float* arow = Bx + 2048 + (h * 16 + c) * 32;
        float a = 0.f;
        #pragma unroll
        for (int p = 0; p < 32; ++p) a = fmaf(xi[p * 128 + h * 32 + d], arow[p], a);
        A[2048 + e] = a;
    }
    __syncthreads();

    // --- vpatch[p][h*32+d] = sum_c vcore[h][c][d] * ap2c[h][c][p] -> vout = Bx[0:4096]
    for (int e = t; e < 4096; e += 256) {
        int d = e & 31, p = (e >> 5) & 31, h = e >> 10;
        const float* vc = A + 2048 + h * 512 + d;    // stride 32 over c
        const float* ap = A + h * 512 + p;           // stride 32 over c
        float a = 0.f;
        #pragma unroll
        for (int c = 0; c < 16; ++c) a = fmaf(vc[c * 32], ap[c * 32], a);
        Bx[p * 128 + h * 32 + d] = a;
    }
    __syncthreads();

    // --- FFN: ffn_in = [xi - vout, vout] (256) -> gelu(@f1w+b1) (1024) -> @f2w+b2
    // hidden processed in 8 chunks of 128 cols, chunk staged in A[0:4096]
    float acc[16];
    #pragma unroll
    for (int i = 0; i < 16; ++i) acc[i] = f2b[c0 + i];
    for (int ch = 0; ch < 8; ++ch) {
        const int h0 = ch * 128;
        float hv[16];
        #pragma unroll
        for (int i = 0; i < 16; ++i) hv[i] = f1b[h0 + c0 + i];
        for (int k = 0; k < 128; ++k) {              // first half: xi - vout
            float fv = xi[r * 128 + k] - Bx[r * 128 + k];
            const float* wrow = f1w + k * 1024 + h0 + c0;
            #pragma unroll
            for (int i = 0; i < 16; ++i) hv[i] = fmaf(fv, wrow[i], hv[i]);
        }
        for (int k = 0; k < 128; ++k) {              // second half: vout
            float fv = Bx[r * 128 + k];
            const float* wrow = f1w + (128 + k) * 1024 + h0 + c0;
            #pragma unroll
            for (int i = 0; i < 16; ++i) hv[i] = fmaf(fv, wrow[i], hv[i]);
        }
        if (ch) __syncthreads();                     // prior stage-2 reads done
        #pragma unroll
        for (int i = 0; i < 16; ++i) A[r * 128 + c0 + i] = gelu_f(hv[i]);
        __syncthreads();
        for (int j = 0; j < 128; ++j) {
            float hj = A[r * 128 + j];
            const float* w2r = f2w + (h0 + j) * 128 + c0;
            #pragma unroll
            for (int i = 0; i < 16; ++i) acc[i] = fmaf(hj, w2r[i], acc[i]);
        }
    }

    // --- y = xi + ffn_out; LN(eps=1e-5)*g + b; out = x_orig + y ---
    float yv[16];
    float s2 = 0.f, ss2 = 0.f;
    #pragma unroll
    for (int i = 0; i < 16; ++i) {
        yv[i] = xi[r * 128 + c0 + i] + acc[i];
        s2 += yv[i]; ss2 += yv[i] * yv[i];
    }
    #pragma unroll
    for (int msk = 1; msk < 8; msk <<= 1) {
        s2  += __shfl_xor(s2,  msk);
        ss2 += __shfl_xor(ss2, msk);
    }
    float mean2 = s2 * (1.f / 128.f);
    float var2  = ss2 * (1.f / 128.f) - mean2 * mean2;
    float inv2  = rsqrtf(var2 + 1e-5f);
    float* orow = out + (baseTok + (long)r * 16) * 128 + c0;
    #pragma unroll
    for (int i = 0; i < 16; ++i)
        orow[i] = v0[i] + ((yv[i] - mean2) * inv2) * ng[c0 + i] + nb[c0 + i];
}

// ---------------------------------------------------------------------------
// Token-wise residual MLP:  x += gelu(LN(x,1e-6) @ w1 + b1) @ w2 + b2
// 32 tokens per block, 256 threads, hidden chunked by 128. In-place on xio.
// ---------------------------------------------------------------------------
template <int HID>
__global__ __launch_bounds__(256)
void mlp_residual_kernel(float* __restrict__ xio,
                         const float* __restrict__ w1, const float* __restrict__ b1,
                         const float* __restrict__ w2, const float* __restrict__ b2)
{
    constexpr int NCH = HID / 128;
    __shared__ float xn[4096];
    __shared__ float hid[4096];
    const int t   = threadIdx.x;
    const int r   = t >> 3;
    const int sub = t & 7;
    const int c0  = sub * 16;
    const long baseTok = (long)blockIdx.x * 32;
    float* xrow = xio + (baseTok + r) * 128 + c0;

    float v0[16];
    float s = 0.f, ss = 0.f;
    #pragma unroll
    for (int i = 0; i < 16; ++i) { v0[i] = xrow[i]; s += v0[i]; ss += v0[i] * v0[i]; }
    #pragma unroll
    for (int msk = 1; msk < 8; msk <<= 1) {
        s  += __shfl_xor(s,  msk);
        ss += __shfl_xor(ss, msk);
    }
    {
        float mean = s * (1.f / 128.f);
        float var  = ss * (1.f / 128.f) - mean * mean;
        float inv  = rsqrtf(var + 1e-6f);
        #pragma unroll
        for (int i = 0; i < 16; ++i) xn[r * 128 + c0 + i] = (v0[i] - mean) * inv;
    }
    __syncthreads();

    float acc[16];
    #pragma unroll
    for (int i = 0; i < 16; ++i) acc[i] = b2[c0 + i];
    for (int ch = 0; ch < NCH; ++ch) {
        const int h0 = ch * 128;
        float hv[16];
        #pragma unroll
        for (int i = 0; i < 16; ++i) hv[i] = b1[h0 + c0 + i];
        for (int k = 0; k < 128; ++k) {
            float xv = xn[r * 128 + k];
            const float* wrow = w1 + k * HID + h0 + c0;
            #pragma unroll
            for (int i = 0; i < 16; ++i) hv[i] = fmaf(xv, wrow[i], hv[i]);
        }
        if (ch) __syncthreads();
        #pragma unroll
        for (int i = 0; i < 16; ++i) hid[r * 128 + c0 + i] = gelu_f(hv[i]);
        __syncthreads();
        for (int j = 0; j < 128; ++j) {
            float hj = hid[r * 128 + j];
            const float* w2r = w2 + (h0 + j) * 128 + c0;
            #pragma unroll
            for (int i = 0; i < 16; ++i) acc[i] = fmaf(hj, w2r[i], acc[i]);
        }
    }
    #pragma unroll
    for (int i = 0; i < 16; ++i) xrow[i] = v0[i] + acc[i];
}

// ---------------------------------------------------------------------------
extern "C" void kernel_launch(void* const* d_in, const int* in_sizes, int n_in,
                              void* d_out, int out_size, void* d_ws, size_t ws_size,
                              hipStream_t stream)
{
    (void)in_sizes; (void)n_in; (void)d_ws; (void)ws_size; (void)out_size;

    const float* x     = (const float*)d_in[0];
    const float* cores = (const float*)d_in[1];
    const float* vw    = (const float*)d_in[2];
    const float* vbb   = (const float*)d_in[3];
    const float* f1w   = (const float*)d_in[4];
    const float* f1b   = (const float*)d_in[5];
    const float* f2w   = (const float*)d_in[6];
    const float* f2b   = (const float*)d_in[7];
    const float* ng    = (const float*)d_in[8];
    const float* nbv   = (const float*)d_in[9];
    const float* im1w  = (const float*)d_in[10];
    const float* im1b  = (const float*)d_in[11];
    const float* im2w  = (const float*)d_in[12];
    const float* im2b  = (const float*)d_in[13];
    const float* ii1w  = (const float*)d_in[14];
    const float* ii1b  = (const float*)d_in[15];
    const float* ii2w  = (const float*)d_in[16];
    const float* ii2b  = (const float*)d_in[17];
    const float* am1w  = (const float*)d_in[18];
    const float* am1b  = (const float*)d_in[19];
    const float* am2w  = (const float*)d_in[20];
    const float* am2b  = (const float*)d_in[21];
    float* out = (float*)d_out;

    // 1) inter-patch PCI: out = x + inter
    hipLaunchKernelGGL(pci_inter_kernel, dim3(4096), dim3(256), 0, stream,
                       x, cores, vw, vbb, f1w, f1b, f2w, f2b, ng, nbv, out);
    // 2) x += MLP_512(LN(x))
    hipLaunchKernelGGL((mlp_residual_kernel<512>), dim3(4096), dim3(256), 0, stream,
                       out, im1w, im1b, im2w, im2b);
    // 3) x += MLP_128(LN(x))   (intra interaction, pointwise)
    hipLaunchKernelGGL((mlp_residual_kernel<128>), dim3(4096), dim3(256), 0, stream,
                       out, ii1w, ii1b, ii2w, ii2b);
    // 4) x += MLP_512(LN(x))
    hipLaunchKernelGGL((mlp_residual_kernel<512>), dim3(4096), dim3(256), 0, stream,
                       out, am1w, am1b, am2w, am2b);
}

// Round 6
// 18849.681 us; speedup vs baseline: 1.0230x; 1.0230x over previous
//
#include <hip/hip_runtime.h>
#include <hip/hip_bf16.h>
#include <math.h>

// B=8, T=32, P=32, N=16, D=128, H=4, C=16, HD=32, FFN_PCI=1024, MLP_H=512
// tokens = 131072; x[bt][p][n][d] flat: bt*65536 + p*2048 + n*128 + d

typedef unsigned short u16;
typedef unsigned int   u32;
typedef __attribute__((ext_vector_type(8))) short bf16x8;
typedef __attribute__((ext_vector_type(4))) float f32x4;

static __device__ __forceinline__ f32x4 mfma16(bf16x8 a, bf16x8 b, f32x4 c) {
    return __builtin_amdgcn_mfma_f32_16x16x32_bf16(a, b, c, 0, 0, 0);
}
static __device__ __forceinline__ u16 f2bf(float f) {
    u32 u = __builtin_bit_cast(u32, f);
    u32 r = (u + 0x7FFFu + ((u >> 16) & 1u)) >> 16;   // RNE
    return (u16)r;
}
static __device__ __forceinline__ float gelu_f(float v) {
    return 0.5f * v * (1.0f + erff(v * 0.70710678118654752f));
}

// ---------------------------------------------------------------------------
// vw transpose+convert: fp32 [128][128] -> bf16 [N][K]=[128][128] in d_ws.
// ---------------------------------------------------------------------------
__global__ __launch_bounds__(256)
void transpose_vw(const float* __restrict__ src, u16* __restrict__ dst)
{
    __shared__ float tile[32][33];
    int tt = blockIdx.x;                 // 16 tiles: 4x4 of 32x32
    int n0 = (tt & 3) << 5, k0 = (tt >> 2) << 5;
    int tx = threadIdx.x & 31, ty = threadIdx.x >> 5;    // 32 x 8
    for (int i = ty; i < 32; i += 8) tile[i][tx] = src[(size_t)(k0 + i) * 128 + n0 + tx];
    __syncthreads();
    for (int i = ty; i < 32; i += 8) dst[(size_t)(n0 + i) * 128 + k0 + tx] = f2bf(tile[tx][i]);
}

// ---------------------------------------------------------------------------
// PCI kernel (R1's proven fp32 kernel; ONLY the q-projection is MFMA).
// grid = 4096 (bt,n) groups, 256 threads.
// LDS: xi f32[4096] | A f32[4160] (q[32][129] -> {ap2c,vcore} -> hidden)
//      | Bx f32[4096] (aff/ac2p -> vout) | xb u16[4096] (xi bf16, linear)
// ---------------------------------------------------------------------------
__global__ __launch_bounds__(256)
void pci_inter_kernel(const float* __restrict__ x,
                      const float* __restrict__ cores,   // [4][16][32]
                      const u16*   __restrict__ vwT,     // bf16 [128][128] = vw^T
                      const float* __restrict__ vb,      // [128]
                      const float* __restrict__ f1w,     // [256][1024]
                      const float* __restrict__ f1b,     // [1024]
                      const float* __restrict__ f2w,     // [1024][128]
                      const float* __restrict__ f2b,     // [128]
                      const float* __restrict__ ng,      // [128]
                      const float* __restrict__ nb,      // [128]
                      float* __restrict__ out)
{
    __shared__ float xi[4096];
    __shared__ float A[4160];
    __shared__ float Bx[4096];
    __shared__ u16   xb[4096];

    const int t   = threadIdx.x;
    const int r   = t >> 3;      // row 0..31 (patch p)
    const int sub = t & 7;
    const int c0  = sub * 16;
    const int lane = t & 63;
    const int w    = t >> 6;

    const int m  = blockIdx.x;
    const int n  = m & 15;
    const int bt = m >> 4;
    const long baseTok = (long)bt * 512 + n;   // token of row p is baseTok + p*16
    const float* xrow = x + (baseTok + (long)r * 16) * 128 + c0;

    // --- LN(eps=1e-6, non-affine) -> xi (f32) + xb (bf16, linear [32][128]) ---
    float v0[16];
    float s = 0.f, ss = 0.f;
    #pragma unroll
    for (int i = 0; i < 16; ++i) {
        v0[i] = xrow[i];
        s += v0[i]; ss += v0[i] * v0[i];
    }
    #pragma unroll
    for (int msk = 1; msk < 8; msk <<= 1) {
        s  += __shfl_xor(s,  msk);
        ss += __shfl_xor(ss, msk);
    }
    {
        float mean = s * (1.f / 128.f);
        float var  = ss * (1.f / 128.f) - mean * mean;
        float inv  = rsqrtf(var + 1e-6f);
        #pragma unroll
        for (int i = 0; i < 16; ++i) {
            float a = (v0[i] - mean) * inv;
            xi[r * 128 + c0 + i] = a;
            xb[r * 128 + c0 + i] = f2bf(a);
        }
    }
    __syncthreads();

    // --- q = xi @ vw + vb via MFMA -> A as q[32][129] f32 (padded, plain) ---
    {
        f32x4 acc[2][2] = {};
        bf16x8 a[2][4];
        #pragma unroll
        for (int mt = 0; mt < 2; ++mt)
            #pragma unroll
            for (int ks = 0; ks < 4; ++ks)
                a[mt][ks] = *reinterpret_cast<const bf16x8*>(
                    xb + (mt * 16 + (lane & 15)) * 128 + ks * 32 + ((lane >> 4) << 3));
        #pragma unroll
        for (int nt = 0; nt < 2; ++nt) {
            int n0 = w * 32 + nt * 16;
            #pragma unroll
            for (int ks = 0; ks < 4; ++ks) {
                // B-frag: vwT [n][k], lane&15 -> n, 8 contiguous k by lane>>4
                bf16x8 b = *reinterpret_cast<const bf16x8*>(
                    vwT + (size_t)(n0 + (lane & 15)) * 128 + ks * 32 + ((lane >> 4) << 3));
                acc[0][nt] = mfma16(a[0][ks], b, acc[0][nt]);
                acc[1][nt] = mfma16(a[1][ks], b, acc[1][nt]);
            }
        }
        // C/D decode: col = lane&15, row = (lane>>4)*4 + reg
        #pragma unroll
        for (int nt = 0; nt < 2; ++nt) {
            int col = w * 32 + nt * 16 + (lane & 15);
            float bias = vb[col];
            #pragma unroll
            for (int rr = 0; rr < 4; ++rr) {
                int row0 = ((lane >> 4) << 2) + rr;
                A[row0 * 129 + col]        = acc[0][nt][rr] + bias;
                A[(row0 + 16) * 129 + col] = acc[1][nt][rr] + bias;
            }
        }
    }
    __syncthreads();

    // --- aff[h][c][p] = cores . q / sqrt(32) -> Bx[0:2048] ---
    for (int e = t; e < 2048; e += 256) {
        int p = e & 31, c = (e >> 5) & 15, h = e >> 9;
        const float* cr = cores + (h * 16 + c) * 32;
        const float* qr = A + p * 129 + h * 32;
        float a = 0.f;
        #pragma unroll
        for (int d = 0; d < 32; ++d) a = fmaf(cr[d], qr[d], a);
        Bx[e] = a * 0.17677669529663687f;   // 1/sqrt(32)
    }
    __syncthreads();

    // --- softmaxes: ac2p (over p) -> Bx[2048:4096];  ap2c (over c) -> A[0:2048]
    if (t < 64) {
        const float* arow = Bx + t * 32;             // (h,c) row
        float mx = -1e30f;
        #pragma unroll
        for (int p = 0; p < 32; ++p) mx = fmaxf(mx, arow[p]);
        float ex[32]; float sm = 0.f;
        #pragma unroll
        for (int p = 0; p < 32; ++p) { ex[p] = expf(arow[p] - mx); sm += ex[p]; }
        float is = 1.f / sm;
        #pragma unroll
        for (int p = 0; p < 32; ++p) Bx[2048 + t * 32 + p] = ex[p] * is;
    } else if (t < 192) {
        int u = t - 64;
        int h = u >> 5, p = u & 31;
        const float* ab = Bx + h * 512 + p;          // aff[h][c][p], stride 32 over c
        float mx = -1e30f;
        #pragma unroll
        for (int c = 0; c < 16; ++c) mx = fmaxf(mx, ab[c * 32]);
        float ex[16]; float sm = 0.f;
        #pragma unroll
        for (int c = 0; c < 16; ++c) { ex[c] = expf(ab[c * 32] - mx); sm += ex[c]; }
        float is = 1.f / sm;
        #pragma unroll
        for (int c = 0; c < 16; ++c) A[h * 512 + c * 32 + p] = ex[c] * is;
    }
    __syncthreads();

    // --- vcore[h][c][d] = sum_p xi[p][h*32+d] * ac2p[h][c][p] -> A[2048:4096]
    for (int e = t; e < 2048; e += 256) {
        int d = e & 31, c = (e >> 5) & 15, h = e >> 9;
        const float* arow = Bx + 2048 + (h * 16 + c) * 32;
        float a = 0.f;
        #pragma unroll
        for (int p = 0; p < 32; ++p) a = fmaf(xi[p * 128 + h * 32 + d], arow[p], a);
        A[2048 + e] = a;
    }
    __syncthreads();

    // --- vpatch[p][h*32+d] = sum_c vcore[h][c][d] * ap2c[h][c][p] -> vout = Bx[0:4096]
    for (int e = t; e < 4096; e += 256) {
        int d = e & 31, p = (e >> 5) & 31, h = e >> 10;
        const float* vc = A + 2048 + h * 512 + d;    // stride 32 over c
        const float* ap = A + h * 512 + p;           // stride 32 over c
        float a = 0.f;
        #pragma unroll
        for (int c = 0; c < 16; ++c) a = fmaf(vc[c * 32], ap[c * 32], a);
        Bx[p * 128 + h * 32 + d] = a;
    }
    __syncthreads();

    // --- FFN: ffn_in = [xi - vout, vout] (256) -> gelu(@f1w+b1) (1024) -> @f2w+b2
    // hidden processed in 8 chunks of 128 cols, chunk staged in A[0:4096]
    float acc[16];
    #pragma unroll
    for (int i = 0; i < 16; ++i) acc[i] = f2b[c0 + i];
    for (int ch = 0; ch < 8; ++ch) {
        const int h0 = ch * 128;
        float hv[16];
        #pragma unroll
        for (int i = 0; i < 16; ++i) hv[i] = f1b[h0 + c0 + i];
        for (int k = 0; k < 128; ++k) {              // first half: xi - vout
            float fv = xi[r * 128 + k] - Bx[r * 128 + k];
            const float* wrow = f1w + k * 1024 + h0 + c0;
            #pragma unroll
            for (int i = 0; i < 16; ++i) hv[i] = fmaf(fv, wrow[i], hv[i]);
        }
        for (int k = 0; k < 128; ++k) {              // second half: vout
            float fv = Bx[r * 128 + k];
            const float* wrow = f1w + (128 + k) * 1024 + h0 + c0;
            #pragma unroll
            for (int i = 0; i < 16; ++i) hv[i] = fmaf(fv, wrow[i], hv[i]);
        }
        if (ch) __syncthreads();                     // prior stage-2 reads done
        #pragma unroll
        for (int i = 0; i < 16; ++i) A[r * 128 + c0 + i] = gelu_f(hv[i]);
        __syncthreads();
        for (int j = 0; j < 128; ++j) {
            float hj = A[r * 128 + j];
            const float* w2r = f2w + (h0 + j) * 128 + c0;
            #pragma unroll
            for (int i = 0; i < 16; ++i) acc[i] = fmaf(hj, w2r[i], acc[i]);
        }
    }

    // --- y = xi + ffn_out; LN(eps=1e-5)*g + b; out = x_orig + y ---
    float yv[16];
    float s2 = 0.f, ss2 = 0.f;
    #pragma unroll
    for (int i = 0; i < 16; ++i) {
        yv[i] = xi[r * 128 + c0 + i] + acc[i];
        s2 += yv[i]; ss2 += yv[i] * yv[i];
    }
    #pragma unroll
    for (int msk = 1; msk < 8; msk <<= 1) {
        s2  += __shfl_xor(s2,  msk);
        ss2 += __shfl_xor(ss2, msk);
    }
    float mean2 = s2 * (1.f / 128.f);
    float var2  = ss2 * (1.f / 128.f) - mean2 * mean2;
    float inv2  = rsqrtf(var2 + 1e-5f);
    float* orow = out + (baseTok + (long)r * 16) * 128 + c0;
    #pragma unroll
    for (int i = 0; i < 16; ++i)
        orow[i] = v0[i] + ((yv[i] - mean2) * inv2) * ng[c0 + i] + nb[c0 + i];
}

// ---------------------------------------------------------------------------
// Token-wise residual MLP (R1's proven fp32 kernel, verbatim):
//   x += gelu(LN(x,1e-6) @ w1 + b1) @ w2 + b2
// ---------------------------------------------------------------------------
template <int HID>
__global__ __launch_bounds__(256)
void mlp_residual_kernel(float* __restrict__ xio,
                         const float* __restrict__ w1, const float* __restrict__ b1,
                         const float* __restrict__ w2, const float* __restrict__ b2)
{
    constexpr int NCH = HID / 128;
    __shared__ float xn[4096];
    __shared__ float hid[4096];
    const int t   = threadIdx.x;
    const int r   = t >> 3;
    const int sub = t & 7;
    const int c0  = sub * 16;
    const long baseTok = (long)blockIdx.x * 32;
    float* xrow = xio + (baseTok + r) * 128 + c0;

    float v0[16];
    float s = 0.f, ss = 0.f;
    #pragma unroll
    for (int i = 0; i < 16; ++i) { v0[i] = xrow[i]; s += v0[i]; ss += v0[i] * v0[i]; }
    #pragma unroll
    for (int msk = 1; msk < 8; msk <<= 1) {
        s  += __shfl_xor(s,  msk);
        ss += __shfl_xor(ss, msk);
    }
    {
        float mean = s * (1.f / 128.f);
        float var  = ss * (1.f / 128.f) - mean * mean;
        float inv  = rsqrtf(var + 1e-6f);
        #pragma unroll
        for (int i = 0; i < 16; ++i) xn[r * 128 + c0 + i] = (v0[i] - mean) * inv;
    }
    __syncthreads();

    float acc[16];
    #pragma unroll
    for (int i = 0; i < 16; ++i) acc[i] = b2[c0 + i];
    for (int ch = 0; ch < NCH; ++ch) {
        const int h0 = ch * 128;
        float hv[16];
        #pragma unroll
        for (int i = 0; i < 16; ++i) hv[i] = b1[h0 + c0 + i];
        for (int k = 0; k < 128; ++k) {
            float xv = xn[r * 128 + k];
            const float* wrow = w1 + k * HID + h0 + c0;
            #pragma unroll
            for (int i = 0; i < 16; ++i) hv[i] = fmaf(xv, wrow[i], hv[i]);
        }
        if (ch) __syncthreads();
        #pragma unroll
        for (int i = 0; i < 16; ++i) hid[r * 128 + c0 + i] = gelu_f(hv[i]);
        __syncthreads();
        for (int j = 0; j < 128; ++j) {
            float hj = hid[r * 128 + j];
            const float* w2r = w2 + (h0 + j) * 128 + c0;
            #pragma unroll
            for (int i = 0; i < 16; ++i) acc[i] = fmaf(hj, w2r[i], acc[i]);
        }
    }
    #pragma unroll
    for (int i = 0; i < 16; ++i) xrow[i] = v0[i] + acc[i];
}

// ---------------------------------------------------------------------------
extern "C" void kernel_launch(void* const* d_in, const int* in_sizes, int n_in,
                              void* d_out, int out_size, void* d_ws, size_t ws_size,
                              hipStream_t stream)
{
    (void)in_sizes; (void)n_in; (void)ws_size; (void)out_size;

    const float* x     = (const float*)d_in[0];
    const float* cores = (const float*)d_in[1];
    const float* vw    = (const float*)d_in[2];
    const float* vbb   = (const float*)d_in[3];
    const float* f1w   = (const float*)d_in[4];
    const float* f1b   = (const float*)d_in[5];
    const float* f2w   = (const float*)d_in[6];
    const float* f2b   = (const float*)d_in[7];
    const float* ng    = (const float*)d_in[8];
    const float* nbv   = (const float*)d_in[9];
    const float* im1w  = (const float*)d_in[10];
    const float* im1b  = (const float*)d_in[11];
    const float* im2w  = (const float*)d_in[12];
    const float* im2b  = (const float*)d_in[13];
    const float* ii1w  = (const float*)d_in[14];
    const float* ii1b  = (const float*)d_in[15];
    const float* ii2w  = (const float*)d_in[16];
    const float* ii2b  = (const float*)d_in[17];
    const float* am1w  = (const float*)d_in[18];
    const float* am1b  = (const float*)d_in[19];
    const float* am2w  = (const float*)d_in[20];
    const float* am2b  = (const float*)d_in[21];
    float* out = (float*)d_out;

    u16* vwT = (u16*)d_ws;   // bf16 vw^T [128][128]

    hipLaunchKernelGGL(transpose_vw, dim3(16), dim3(256), 0, stream, vw, vwT);

    // 1) inter-patch PCI (fp32 everywhere except MFMA q-projection)
    hipLaunchKernelGGL(pci_inter_kernel, dim3(4096), dim3(256), 0, stream,
                       x, cores, vwT, vbb, f1w, f1b, f2w, f2b, ng, nbv, out);
    // 2-4) token MLPs, proven fp32
    hipLaunchKernelGGL((mlp_residual_kernel<512>), dim3(4096), dim3(256), 0, stream,
                       out, im1w, im1b, im2w, im2b);
    hipLaunchKernelGGL((mlp_residual_kernel<128>), dim3(4096), dim3(256), 0, stream,
                       out, ii1w, ii1b, ii2w, ii2b);
    hipLaunchKernelGGL((mlp_residual_kernel<512>), dim3(4096), dim3(256), 0, stream,
                       out, am1w, am1b, am2w, am2b);
}